// Round 3
// baseline (32.639 us; speedup 1.0000x reference)
//
#include <hip/hip_runtime.h>

#define MV 16

typedef __attribute__((ext_vector_type(8))) short short8;
typedef __attribute__((ext_vector_type(4))) float f32x4;

// ---------------------------------------------------------------------------
// out[p,i] = sum_{j,k} gp[i,j,k] * x[p,j] * y[p,k]  via mfma_f32_16x16x32_bf16:
// per 16-pixel tile: D[16pix x 16i] = sum_{c=0..7} A_c[16x32] B_c[32x16]
//
// K-axis relabeling (verified MFMA layouts from R2: A row=l&15 kidx=8*(l>>4)+e,
// B col=l&15 kidx=8*(l>>4)+e, D col=l&15 row=4*(l>>4)+r):
//   chunk c, group g=l>>4, elem e:  j = 8*(g>>1) + c,  k = 8*(g&1) + e
// => per lane: x-slice x[p][8ja..8ja+7] and y-slice y[p][8kb..8kb+7], both
//    contiguous (2 float4 each, 64 B/lane total) and fully used.
// B fragment: lane (g, i=l&15) elem e of chunk c = gp[i][8ja+c][8kb+e],
// built in-kernel from gp (16 KiB, cache-resident) — no pack kernel.
// ---------------------------------------------------------------------------
template <int TPW, bool GUARD>
__global__ __launch_bounds__(256) void gp_mfma_kernel(
    const float* __restrict__ gp,
    const float* __restrict__ x,
    const float* __restrict__ y,
    float* __restrict__ out,
    int ntiles)
{
    const int lane = threadIdx.x & 63;
    const int wid  = threadIdx.x >> 6;
    const int g    = lane >> 4;
    const int p    = lane & 15;       // A row (pixel-in-tile) / B col (i)
    const int ja   = g >> 1;
    const int kb   = g & 1;

    // ---- B fragments, once per wave (amortized over TPW tiles) ----
    short8 bfrag[8];
    {
        const float* gb = gp + ((p * MV + 8 * ja) * MV + 8 * kb);
        #pragma unroll
        for (int c = 0; c < 8; ++c) {
            float4 g0 = *reinterpret_cast<const float4*>(gb + c * MV);
            float4 g1 = *reinterpret_cast<const float4*>(gb + c * MV + 4);
            float gv[8] = {g0.x, g0.y, g0.z, g0.w, g1.x, g1.y, g1.z, g1.w};
            short8 b;
            #pragma unroll
            for (int e = 0; e < 8; ++e) {
                __bf16 h = (__bf16)gv[e];
                b[e] = __builtin_bit_cast(short, h);
            }
            bfrag[c] = b;
        }
    }

    const int tile0 = (blockIdx.x * 4 + wid) * TPW;

    #pragma unroll
    for (int t = 0; t < TPW; ++t) {
        int tile = tile0 + t;
        if (GUARD && tile >= ntiles) continue;

        const float* xp = x + ((size_t)tile * 16 + p) * MV + 8 * ja;
        const float* yp = y + ((size_t)tile * 16 + p) * MV + 8 * kb;

        float4 xv0 = *reinterpret_cast<const float4*>(xp);
        float4 xv1 = *reinterpret_cast<const float4*>(xp + 4);
        float4 yv0 = *reinterpret_cast<const float4*>(yp);
        float4 yv1 = *reinterpret_cast<const float4*>(yp + 4);

        float xs[8] = {xv0.x, xv0.y, xv0.z, xv0.w, xv1.x, xv1.y, xv1.z, xv1.w};
        float ys[8] = {yv0.x, yv0.y, yv0.z, yv0.w, yv1.x, yv1.y, yv1.z, yv1.w};

        f32x4 acc = {0.f, 0.f, 0.f, 0.f};
        #pragma unroll
        for (int c = 0; c < 8; ++c) {
            float xj = xs[c];
            short8 a;
            #pragma unroll
            for (int e = 0; e < 8; ++e) {
                __bf16 h = (__bf16)(xj * ys[e]);   // z[p, jk] rounded once (RNE)
                a[e] = __builtin_bit_cast(short, h);
            }
            acc = __builtin_amdgcn_mfma_f32_16x16x32_bf16(a, bfrag[c], acc, 0, 0, 0);
        }

        // D: col = lane&15 (=i), rows 4g..4g+3 (=pixels)
        float* op = out + ((size_t)tile * 16 + 4 * g) * MV + p;
        op[0 * MV] = acc[0];
        op[1 * MV] = acc[1];
        op[2 * MV] = acc[2];
        op[3 * MV] = acc[3];
    }
}

// ---------------------------------------------------------------------------
// fp32 fallback for shapes the MFMA path doesn't cover
// ---------------------------------------------------------------------------
__global__ __launch_bounds__(256) void gp_fp32_kernel(
    const float* __restrict__ g,
    const float* __restrict__ x,
    const float* __restrict__ y,
    float* __restrict__ out,
    int npix)
{
    int idx = blockIdx.x * blockDim.x + threadIdx.x;
    if (idx >= npix) return;

    const float4* xv = reinterpret_cast<const float4*>(x) + (size_t)idx * 4;
    const float4* yv = reinterpret_cast<const float4*>(y) + (size_t)idx * 4;

    float xr[MV], yr[MV], acc[MV];
    #pragma unroll
    for (int q = 0; q < 4; ++q) {
        float4 t = xv[q];
        xr[4*q+0] = t.x; xr[4*q+1] = t.y; xr[4*q+2] = t.z; xr[4*q+3] = t.w;
        float4 u = yv[q];
        yr[4*q+0] = u.x; yr[4*q+1] = u.y; yr[4*q+2] = u.z; yr[4*q+3] = u.w;
    }
    #pragma unroll
    for (int i = 0; i < MV; ++i) acc[i] = 0.0f;

    #pragma unroll
    for (int j = 0; j < MV; ++j) {
        #pragma unroll
        for (int k = 0; k < MV; ++k) {
            float pr = xr[j] * yr[k];
            #pragma unroll
            for (int i = 0; i < MV; ++i)
                acc[i] = fmaf(g[(i * MV + j) * MV + k], pr, acc[i]);
        }
    }

    float4* ov = reinterpret_cast<float4*>(out) + (size_t)idx * 4;
    #pragma unroll
    for (int q = 0; q < 4; ++q)
        ov[q] = make_float4(acc[4*q+0], acc[4*q+1], acc[4*q+2], acc[4*q+3]);
}

extern "C" void kernel_launch(void* const* d_in, const int* in_sizes, int n_in,
                              void* d_out, int out_size, void* d_ws, size_t ws_size,
                              hipStream_t stream) {
    const float* gp = (const float*)d_in[0];   // [16,16,16]
    const float* x  = (const float*)d_in[1];   // [npix,16]
    const float* y  = (const float*)d_in[2];   // [npix,16]
    float* out      = (float*)d_out;           // [npix,16]

    int npix = in_sizes[1] / MV;
    constexpr int TPW = 4;

    if ((npix % 16) == 0) {
        int ntiles = npix / 16;
        if (ntiles % (4 * TPW) == 0) {
            int blocks = ntiles / (4 * TPW);   // 2048 for npix=524288
            gp_mfma_kernel<TPW, false><<<blocks, 256, 0, stream>>>(gp, x, y, out, ntiles);
        } else {
            int blocks = (ntiles + 4 * TPW - 1) / (4 * TPW);
            gp_mfma_kernel<TPW, true><<<blocks, 256, 0, stream>>>(gp, x, y, out, ntiles);
        }
    } else {
        int blocks = (npix + 255) / 256;
        gp_fp32_kernel<<<blocks, 256, 0, stream>>>(gp, x, y, out, npix);
    }
}

// Round 4
// 29.688 us; speedup vs baseline: 1.0994x; 1.0994x over previous
//
#include <hip/hip_runtime.h>

#define MV 16

typedef __attribute__((ext_vector_type(8))) short short8;
typedef __attribute__((ext_vector_type(4))) float f32x4;

// ---------------------------------------------------------------------------
// Pack gp[i][j][k] (fp32) into per-lane B-fragment layout for
// mfma_f32_16x16x32_bf16 with the R3 jk-labeling:
//   gpbf[(c*64 + lane)*8 + e] = bf16( gp[i][j][k] )
//   i = lane&15, g = lane>>4, j = 8*(g>>1)+c, k = 8*(g&1)+e
// Main kernel loads bfrag[c] as one fully-coalesced 16B/lane load (1 KB/wave).
// ---------------------------------------------------------------------------
__global__ void gp_pack_kernel(const float* __restrict__ gp,
                               unsigned short* __restrict__ gpbf) {
    int t = blockIdx.x * blockDim.x + threadIdx.x;
    if (t < 4096) {
        int e    = t & 7;
        int lane = (t >> 3) & 63;
        int c    = t >> 9;
        int i = lane & 15, g = lane >> 4;
        int j = 8 * (g >> 1) + c;
        int k = 8 * (g & 1) + e;
        __bf16 h = (__bf16)gp[(i * MV + j) * MV + k];
        gpbf[t] = __builtin_bit_cast(unsigned short, h);
    }
}

// ---------------------------------------------------------------------------
// out[p,i] = sum_{j,k} gp[i,j,k]*x[p,j]*y[p,k] as 8x mfma_f32_16x16x32_bf16
// per 16-pixel tile. Lane (g=l>>4, p=l&15): A elems are x[p,8*(g>>1)+c] *
// y[p,8*(g&1)+e] -> per lane 2 contiguous float4 of x + 2 of y, fully used.
// Depth-1 software pipeline: next tile's loads issued before current compute.
// ---------------------------------------------------------------------------
template <int TPW, bool GUARD>
__global__ __launch_bounds__(256) void gp_mfma_kernel(
    const unsigned short* __restrict__ gpbf,
    const float* __restrict__ x,
    const float* __restrict__ y,
    float* __restrict__ out,
    int ntiles)
{
    const int lane = threadIdx.x & 63;
    const int wid  = threadIdx.x >> 6;
    const int g    = lane >> 4;
    const int p    = lane & 15;
    const int ja   = g >> 1;
    const int kb   = g & 1;

    // B fragments: 8 coalesced 16B loads from the 8 KiB packed table (L2-hot)
    short8 bfrag[8];
    #pragma unroll
    for (int c = 0; c < 8; ++c)
        bfrag[c] = *reinterpret_cast<const short8*>(gpbf + (size_t)(c * 64 + lane) * 8);

    const int tile0 = (blockIdx.x * 4 + wid) * TPW;
    const size_t xoff = (size_t)p * MV + 8 * ja;
    const size_t yoff = (size_t)p * MV + 8 * kb;

    float4 cx0, cx1, cy0, cy1;
    {
        bool ok = !GUARD || tile0 < ntiles;
        const float* xp = x + (size_t)tile0 * 16 * MV + xoff;
        const float* yp = y + (size_t)tile0 * 16 * MV + yoff;
        if (ok) {
            cx0 = *reinterpret_cast<const float4*>(xp);
            cx1 = *reinterpret_cast<const float4*>(xp + 4);
            cy0 = *reinterpret_cast<const float4*>(yp);
            cy1 = *reinterpret_cast<const float4*>(yp + 4);
        }
    }

    #pragma unroll
    for (int t = 0; t < TPW; ++t) {
        const int tile = tile0 + t;
        const bool cur_ok = !GUARD || tile < ntiles;

        // ---- issue next tile's loads first (hide HBM latency under compute)
        float4 nx0, nx1, ny0, ny1;
        if (t + 1 < TPW) {
            bool nok = !GUARD || (tile + 1) < ntiles;
            const float* xp = x + (size_t)(tile + 1) * 16 * MV + xoff;
            const float* yp = y + (size_t)(tile + 1) * 16 * MV + yoff;
            if (nok) {
                nx0 = *reinterpret_cast<const float4*>(xp);
                nx1 = *reinterpret_cast<const float4*>(xp + 4);
                ny0 = *reinterpret_cast<const float4*>(yp);
                ny1 = *reinterpret_cast<const float4*>(yp + 4);
            }
        }

        // ---- compute current tile
        if (cur_ok) {
            float xs[8] = {cx0.x, cx0.y, cx0.z, cx0.w, cx1.x, cx1.y, cx1.z, cx1.w};
            float ys[8] = {cy0.x, cy0.y, cy0.z, cy0.w, cy1.x, cy1.y, cy1.z, cy1.w};

            f32x4 acc = {0.f, 0.f, 0.f, 0.f};
            #pragma unroll
            for (int c = 0; c < 8; ++c) {
                float xj = xs[c];
                short8 a;
                #pragma unroll
                for (int e = 0; e < 8; ++e) {
                    __bf16 h = (__bf16)(xj * ys[e]);   // z[p,jk], single RNE round
                    a[e] = __builtin_bit_cast(short, h);
                }
                acc = __builtin_amdgcn_mfma_f32_16x16x32_bf16(a, bfrag[c], acc, 0, 0, 0);
            }

            // D: col = lane&15 (=i), rows 4g..4g+3 (=pixels); out written once,
            // never re-read -> nontemporal, keep L2/L3 for x/y
            float* op = out + ((size_t)tile * 16 + 4 * g) * MV + p;
            __builtin_nontemporal_store(acc[0], op + 0 * MV);
            __builtin_nontemporal_store(acc[1], op + 1 * MV);
            __builtin_nontemporal_store(acc[2], op + 2 * MV);
            __builtin_nontemporal_store(acc[3], op + 3 * MV);
        }

        cx0 = nx0; cx1 = nx1; cy0 = ny0; cy1 = ny1;
    }
}

// ---------------------------------------------------------------------------
// fp32 fallback for shapes the MFMA path doesn't cover
// ---------------------------------------------------------------------------
__global__ __launch_bounds__(256) void gp_fp32_kernel(
    const float* __restrict__ g,
    const float* __restrict__ x,
    const float* __restrict__ y,
    float* __restrict__ out,
    int npix)
{
    int idx = blockIdx.x * blockDim.x + threadIdx.x;
    if (idx >= npix) return;

    const float4* xv = reinterpret_cast<const float4*>(x) + (size_t)idx * 4;
    const float4* yv = reinterpret_cast<const float4*>(y) + (size_t)idx * 4;

    float xr[MV], yr[MV], acc[MV];
    #pragma unroll
    for (int q = 0; q < 4; ++q) {
        float4 t = xv[q];
        xr[4*q+0] = t.x; xr[4*q+1] = t.y; xr[4*q+2] = t.z; xr[4*q+3] = t.w;
        float4 u = yv[q];
        yr[4*q+0] = u.x; yr[4*q+1] = u.y; yr[4*q+2] = u.z; yr[4*q+3] = u.w;
    }
    #pragma unroll
    for (int i = 0; i < MV; ++i) acc[i] = 0.0f;

    #pragma unroll
    for (int j = 0; j < MV; ++j) {
        #pragma unroll
        for (int k = 0; k < MV; ++k) {
            float pr = xr[j] * yr[k];
            #pragma unroll
            for (int i = 0; i < MV; ++i)
                acc[i] = fmaf(g[(i * MV + j) * MV + k], pr, acc[i]);
        }
    }

    float4* ov = reinterpret_cast<float4*>(out) + (size_t)idx * 4;
    #pragma unroll
    for (int q = 0; q < 4; ++q)
        ov[q] = make_float4(acc[4*q+0], acc[4*q+1], acc[4*q+2], acc[4*q+3]);
}

extern "C" void kernel_launch(void* const* d_in, const int* in_sizes, int n_in,
                              void* d_out, int out_size, void* d_ws, size_t ws_size,
                              hipStream_t stream) {
    const float* gp = (const float*)d_in[0];   // [16,16,16]
    const float* x  = (const float*)d_in[1];   // [npix,16]
    const float* y  = (const float*)d_in[2];   // [npix,16]
    float* out      = (float*)d_out;           // [npix,16]

    int npix = in_sizes[1] / MV;
    constexpr int TPW = 4;

    if ((npix % 16) == 0 && ws_size >= 4096 * sizeof(unsigned short)) {
        unsigned short* gpbf = (unsigned short*)d_ws;
        gp_pack_kernel<<<16, 256, 0, stream>>>(gp, gpbf);
        int ntiles = npix / 16;
        if (ntiles % (4 * TPW) == 0) {
            int blocks = ntiles / (4 * TPW);   // 2048 for npix=524288
            gp_mfma_kernel<TPW, false><<<blocks, 256, 0, stream>>>(gpbf, x, y, out, ntiles);
        } else {
            int blocks = (ntiles + 4 * TPW - 1) / (4 * TPW);
            gp_mfma_kernel<TPW, true><<<blocks, 256, 0, stream>>>(gpbf, x, y, out, ntiles);
        }
    } else {
        int blocks = (npix + 255) / 256;
        gp_fp32_kernel<<<blocks, 256, 0, stream>>>(gp, x, y, out, npix);
    }
}

// Round 5
// 22.323 us; speedup vs baseline: 1.4621x; 1.3300x over previous
//
#include <hip/hip_runtime.h>

#define MV 16

typedef __attribute__((ext_vector_type(8))) short short8;
typedef __attribute__((ext_vector_type(4))) float f32x4;

// ---------------------------------------------------------------------------
// Fully fused: out[p,i] = sum_{j,k} gp[i,j,k]*x[p,j]*y[p,k] as
// 8x mfma_f32_16x16x32_bf16 per 16-pixel tile.
//
// MFMA layouts (verified R2): A row=l&15, kidx=8*(l>>4)+e; B col=l&15,
// kidx=8*(l>>4)+e; D col=l&15, row=4*(l>>4)+r.
// K-axis labeling: chunk c, group g=l>>4, elem e: j=8*(g>>1)+c, k=8*(g&1)+e
// => per lane 2 contiguous float4 of x + 2 of y per tile, fully used.
//
// B fragments staged per block via LDS (no separate pack dispatch):
//   thread t owns gp[t*16 .. t*16+15] = gp[i=t>>4][j=t&15][k=0..15]
//   (coalesced float4 loads), converts to bf16, writes two short8 at
//   packed index (c*64 + (2*ja+kb)*16 + i)*8 + e  (c=j&7, ja=j>>3).
//   Read side: lane l chunk c = ldsb[(c*64+l)*8 ..+8] -- conflict-free b128.
//
// All TPW tiles' x/y loads are issued up front (16 loads in flight per wave)
// so one HBM latency is paid per wave, not per tile.
// ---------------------------------------------------------------------------
template <int TPW, bool GUARD>
__global__ __launch_bounds__(256) void gp_fused_kernel(
    const float* __restrict__ gp,
    const float* __restrict__ x,
    const float* __restrict__ y,
    float* __restrict__ out,
    int ntiles)
{
    __shared__ unsigned short ldsb[4096];   // 8 KiB packed bf16 table

    const int tid  = threadIdx.x;
    const int lane = tid & 63;
    const int wid  = tid >> 6;
    const int g    = lane >> 4;
    const int p    = lane & 15;
    const int ja   = g >> 1;
    const int kb   = g & 1;

    // ---- gp table loads first (oldest in vmcnt queue) ----
    const float4* gsrc = reinterpret_cast<const float4*>(gp) + tid * 4;
    float4 g0 = gsrc[0], g1 = gsrc[1], g2 = gsrc[2], g3 = gsrc[3];

    // ---- issue all x/y loads for this wave's TPW tiles ----
    const int tile0 = (blockIdx.x * 4 + wid) * TPW;
    const size_t xoff = (size_t)p * MV + 8 * ja;
    const size_t yoff = (size_t)p * MV + 8 * kb;

    float4 xa[TPW][2], ya[TPW][2];
    #pragma unroll
    for (int t = 0; t < TPW; ++t) {
        if (!GUARD || tile0 + t < ntiles) {
            const float* xp = x + (size_t)(tile0 + t) * 16 * MV + xoff;
            const float* yp = y + (size_t)(tile0 + t) * 16 * MV + yoff;
            xa[t][0] = *reinterpret_cast<const float4*>(xp);
            xa[t][1] = *reinterpret_cast<const float4*>(xp + 4);
            ya[t][0] = *reinterpret_cast<const float4*>(yp);
            ya[t][1] = *reinterpret_cast<const float4*>(yp + 4);
        }
    }

    // ---- convert gp row and scatter into packed LDS layout ----
    {
        float gf[16] = {g0.x, g0.y, g0.z, g0.w, g1.x, g1.y, g1.z, g1.w,
                        g2.x, g2.y, g2.z, g2.w, g3.x, g3.y, g3.z, g3.w};
        short8 lo, hi;
        #pragma unroll
        for (int e = 0; e < 8; ++e) {
            __bf16 hl = (__bf16)gf[e];
            __bf16 hh = (__bf16)gf[e + 8];
            lo[e] = __builtin_bit_cast(short, hl);
            hi[e] = __builtin_bit_cast(short, hh);
        }
        const int i = tid >> 4, j = tid & 15;
        const int c = j & 7, jaw = j >> 3;
        unsigned short* d0 = ldsb + ((c * 64 + 32 * jaw) + i) * 8;
        *reinterpret_cast<short8*>(d0)       = lo;   // kb=0: k=0..7
        *reinterpret_cast<short8*>(d0 + 128) = hi;   // kb=1: k=8..15 (+16 lanes)
    }
    __syncthreads();

    short8 bfrag[8];
    #pragma unroll
    for (int c = 0; c < 8; ++c)
        bfrag[c] = *reinterpret_cast<const short8*>(ldsb + (c * 64 + lane) * 8);

    // ---- compute TPW tiles back-to-back ----
    #pragma unroll
    for (int t = 0; t < TPW; ++t) {
        if (GUARD && tile0 + t >= ntiles) continue;

        float xs[8] = {xa[t][0].x, xa[t][0].y, xa[t][0].z, xa[t][0].w,
                       xa[t][1].x, xa[t][1].y, xa[t][1].z, xa[t][1].w};
        float ys[8] = {ya[t][0].x, ya[t][0].y, ya[t][0].z, ya[t][0].w,
                       ya[t][1].x, ya[t][1].y, ya[t][1].z, ya[t][1].w};

        f32x4 acc = {0.f, 0.f, 0.f, 0.f};
        #pragma unroll
        for (int c = 0; c < 8; ++c) {
            float xj = xs[c];
            short8 a;
            #pragma unroll
            for (int e = 0; e < 8; ++e) {
                __bf16 h = (__bf16)(xj * ys[e]);   // z[p,jk], single RNE round
                a[e] = __builtin_bit_cast(short, h);
            }
            acc = __builtin_amdgcn_mfma_f32_16x16x32_bf16(a, bfrag[c], acc, 0, 0, 0);
        }

        // D: col = lane&15 (=i), rows 4g..4g+3 (=pixels)
        float* op = out + ((size_t)(tile0 + t) * 16 + 4 * g) * MV + p;
        op[0 * MV] = acc[0];
        op[1 * MV] = acc[1];
        op[2 * MV] = acc[2];
        op[3 * MV] = acc[3];
    }
}

// ---------------------------------------------------------------------------
// fp32 fallback for shapes the MFMA path doesn't cover
// ---------------------------------------------------------------------------
__global__ __launch_bounds__(256) void gp_fp32_kernel(
    const float* __restrict__ g,
    const float* __restrict__ x,
    const float* __restrict__ y,
    float* __restrict__ out,
    int npix)
{
    int idx = blockIdx.x * blockDim.x + threadIdx.x;
    if (idx >= npix) return;

    const float4* xv = reinterpret_cast<const float4*>(x) + (size_t)idx * 4;
    const float4* yv = reinterpret_cast<const float4*>(y) + (size_t)idx * 4;

    float xr[MV], yr[MV], acc[MV];
    #pragma unroll
    for (int q = 0; q < 4; ++q) {
        float4 t = xv[q];
        xr[4*q+0] = t.x; xr[4*q+1] = t.y; xr[4*q+2] = t.z; xr[4*q+3] = t.w;
        float4 u = yv[q];
        yr[4*q+0] = u.x; yr[4*q+1] = u.y; yr[4*q+2] = u.z; yr[4*q+3] = u.w;
    }
    #pragma unroll
    for (int i = 0; i < MV; ++i) acc[i] = 0.0f;

    #pragma unroll
    for (int j = 0; j < MV; ++j) {
        #pragma unroll
        for (int k = 0; k < MV; ++k) {
            float pr = xr[j] * yr[k];
            #pragma unroll
            for (int i = 0; i < MV; ++i)
                acc[i] = fmaf(g[(i * MV + j) * MV + k], pr, acc[i]);
        }
    }

    float4* ov = reinterpret_cast<float4*>(out) + (size_t)idx * 4;
    #pragma unroll
    for (int q = 0; q < 4; ++q)
        ov[q] = make_float4(acc[4*q+0], acc[4*q+1], acc[4*q+2], acc[4*q+3]);
}

extern "C" void kernel_launch(void* const* d_in, const int* in_sizes, int n_in,
                              void* d_out, int out_size, void* d_ws, size_t ws_size,
                              hipStream_t stream) {
    const float* gp = (const float*)d_in[0];   // [16,16,16]
    const float* x  = (const float*)d_in[1];   // [npix,16]
    const float* y  = (const float*)d_in[2];   // [npix,16]
    float* out      = (float*)d_out;           // [npix,16]

    int npix = in_sizes[1] / MV;
    constexpr int TPW = 4;

    if ((npix % 16) == 0) {
        int ntiles = npix / 16;
        if (ntiles % (4 * TPW) == 0) {
            int blocks = ntiles / (4 * TPW);   // 2048 for npix=524288
            gp_fused_kernel<TPW, false><<<blocks, 256, 0, stream>>>(gp, x, y, out, ntiles);
        } else {
            int blocks = (ntiles + 4 * TPW - 1) / (4 * TPW);
            gp_fused_kernel<TPW, true><<<blocks, 256, 0, stream>>>(gp, x, y, out, ntiles);
        }
    } else {
        int blocks = (npix + 255) / 256;
        gp_fp32_kernel<<<blocks, 256, 0, stream>>>(gp, x, y, out, npix);
    }
}

// Round 6
// 21.172 us; speedup vs baseline: 1.5416x; 1.0544x over previous
//
#include <hip/hip_runtime.h>

#define MV 16

typedef __attribute__((ext_vector_type(8))) short short8;
typedef __attribute__((ext_vector_type(4))) float f32x4;

// ---------------------------------------------------------------------------
// out[p,i] = sum_{j,k} gp[i,j,k]*x[p,j]*y[p,k], 8x mfma_f32_16x16x32_bf16 per
// 16-pixel tile. MFMA layouts (verified R2): A row=l&15, kidx=8*(l>>4)+e;
// B col=l&15, kidx=8*(l>>4)+e; D col=l&15, row=4*(l>>4)+r.
// K labeling: chunk c, group g=l>>4, elem e: j=8*(g>>1)+c, k=8*(g&1)+e
// => per lane per tile: 2 contiguous float4 of x + 2 of y, fully used.
//
// gp staged once per block through LDS into packed per-lane B-fragments
// (layout identical to R5, verified). Persistent grid: each wave owns
// TPWAVE contiguous tiles, processed as ping-pong pairs so the next pair's
// 8 loads are always in flight behind the current pair's compute.
// ---------------------------------------------------------------------------
template <int TPWAVE>
__global__ __launch_bounds__(256, 4) void gp_pipe_kernel(
    const float* __restrict__ gp,
    const float* __restrict__ x,
    const float* __restrict__ y,
    float* __restrict__ out)
{
    __shared__ unsigned short ldsb[4096];   // 8 KiB packed bf16 table

    const int tid  = threadIdx.x;
    const int lane = tid & 63;
    const int wid  = tid >> 6;
    const int g    = lane >> 4;
    const int p    = lane & 15;
    const int ja   = g >> 1;
    const int kb   = g & 1;

    // ---- gp table loads first (oldest in vmcnt queue) ----
    const float4* gsrc = reinterpret_cast<const float4*>(gp) + tid * 4;
    float4 g0 = gsrc[0], g1 = gsrc[1], g2 = gsrc[2], g3 = gsrc[3];

    const int   tile0 = (blockIdx.x * 4 + wid) * TPWAVE;
    const size_t xoff = (size_t)p * MV + 8 * ja;
    const size_t yoff = (size_t)p * MV + 8 * kb;

    // double-buffered pair registers: [buf][tile-in-pair]
    float4 fx0[2][2], fx1[2][2], fy0[2][2], fy1[2][2];

#define LOADTILE(B, T, TILE)                                                   \
    do {                                                                       \
        const float* xp_ = x + (size_t)(TILE) * 16 * MV + xoff;                \
        const float* yp_ = y + (size_t)(TILE) * 16 * MV + yoff;                \
        fx0[B][T] = *reinterpret_cast<const float4*>(xp_);                     \
        fx1[B][T] = *reinterpret_cast<const float4*>(xp_ + 4);                 \
        fy0[B][T] = *reinterpret_cast<const float4*>(yp_);                     \
        fy1[B][T] = *reinterpret_cast<const float4*>(yp_ + 4);                 \
    } while (0)

    // ---- prologue: issue pair 0 loads right behind the gp loads ----
    LOADTILE(0, 0, tile0 + 0);
    LOADTILE(0, 1, tile0 + 1);

    // ---- convert gp row and scatter into packed LDS layout (as R5) ----
    {
        float gf[16] = {g0.x, g0.y, g0.z, g0.w, g1.x, g1.y, g1.z, g1.w,
                        g2.x, g2.y, g2.z, g2.w, g3.x, g3.y, g3.z, g3.w};
        short8 lo, hi;
        #pragma unroll
        for (int e = 0; e < 8; ++e) {
            __bf16 hl = (__bf16)gf[e];
            __bf16 hh = (__bf16)gf[e + 8];
            lo[e] = __builtin_bit_cast(short, hl);
            hi[e] = __builtin_bit_cast(short, hh);
        }
        const int i = tid >> 4, j = tid & 15;
        const int c = j & 7, jaw = j >> 3;
        unsigned short* d0 = ldsb + ((c * 64 + 32 * jaw) + i) * 8;
        *reinterpret_cast<short8*>(d0)       = lo;   // kb=0: k=0..7
        *reinterpret_cast<short8*>(d0 + 128) = hi;   // kb=1: k=8..15
    }
    __syncthreads();

    short8 bfrag[8];
    #pragma unroll
    for (int c = 0; c < 8; ++c)
        bfrag[c] = *reinterpret_cast<const short8*>(ldsb + (c * 64 + lane) * 8);

    // ---- pipelined pair loop: prefetch pair s+1, compute pair s ----
    constexpr int P = TPWAVE / 2;
    #pragma unroll
    for (int s = 0; s < P; ++s) {
        const int cur = s & 1, nxt = cur ^ 1;

        if (s + 1 < P) {
            LOADTILE(nxt, 0, tile0 + 2 * (s + 1) + 0);
            LOADTILE(nxt, 1, tile0 + 2 * (s + 1) + 1);
        }

        #pragma unroll
        for (int tt = 0; tt < 2; ++tt) {
            const int tile = tile0 + 2 * s + tt;
            float xs[8] = {fx0[cur][tt].x, fx0[cur][tt].y, fx0[cur][tt].z, fx0[cur][tt].w,
                           fx1[cur][tt].x, fx1[cur][tt].y, fx1[cur][tt].z, fx1[cur][tt].w};
            float ys[8] = {fy0[cur][tt].x, fy0[cur][tt].y, fy0[cur][tt].z, fy0[cur][tt].w,
                           fy1[cur][tt].x, fy1[cur][tt].y, fy1[cur][tt].z, fy1[cur][tt].w};

            f32x4 acc = {0.f, 0.f, 0.f, 0.f};
            #pragma unroll
            for (int c = 0; c < 8; ++c) {
                float xj = xs[c];
                short8 a;
                #pragma unroll
                for (int e = 0; e < 8; ++e) {
                    __bf16 h = (__bf16)(xj * ys[e]);   // z[p,jk], single RNE round
                    a[e] = __builtin_bit_cast(short, h);
                }
                acc = __builtin_amdgcn_mfma_f32_16x16x32_bf16(a, bfrag[c], acc, 0, 0, 0);
            }

            // D: col = lane&15 (=i), rows 4g..4g+3 (=pixels)
            float* op = out + ((size_t)tile * 16 + 4 * g) * MV + p;
            op[0 * MV] = acc[0];
            op[1 * MV] = acc[1];
            op[2 * MV] = acc[2];
            op[3 * MV] = acc[3];
        }
    }
#undef LOADTILE
}

// ---------------------------------------------------------------------------
// R5 fused kernel (guarded) as fallback for non-divisible shapes
// ---------------------------------------------------------------------------
template <int TPW>
__global__ __launch_bounds__(256) void gp_fused_kernel(
    const float* __restrict__ gp,
    const float* __restrict__ x,
    const float* __restrict__ y,
    float* __restrict__ out,
    int ntiles)
{
    __shared__ unsigned short ldsb[4096];

    const int tid  = threadIdx.x;
    const int lane = tid & 63;
    const int wid  = tid >> 6;
    const int g    = lane >> 4;
    const int p    = lane & 15;
    const int ja   = g >> 1;
    const int kb   = g & 1;

    const float4* gsrc = reinterpret_cast<const float4*>(gp) + tid * 4;
    float4 g0 = gsrc[0], g1 = gsrc[1], g2 = gsrc[2], g3 = gsrc[3];

    const int tile0 = (blockIdx.x * 4 + wid) * TPW;
    const size_t xoff = (size_t)p * MV + 8 * ja;
    const size_t yoff = (size_t)p * MV + 8 * kb;

    float4 xa[TPW][2], ya[TPW][2];
    #pragma unroll
    for (int t = 0; t < TPW; ++t) {
        if (tile0 + t < ntiles) {
            const float* xp = x + (size_t)(tile0 + t) * 16 * MV + xoff;
            const float* yp = y + (size_t)(tile0 + t) * 16 * MV + yoff;
            xa[t][0] = *reinterpret_cast<const float4*>(xp);
            xa[t][1] = *reinterpret_cast<const float4*>(xp + 4);
            ya[t][0] = *reinterpret_cast<const float4*>(yp);
            ya[t][1] = *reinterpret_cast<const float4*>(yp + 4);
        }
    }

    {
        float gf[16] = {g0.x, g0.y, g0.z, g0.w, g1.x, g1.y, g1.z, g1.w,
                        g2.x, g2.y, g2.z, g2.w, g3.x, g3.y, g3.z, g3.w};
        short8 lo, hi;
        #pragma unroll
        for (int e = 0; e < 8; ++e) {
            __bf16 hl = (__bf16)gf[e];
            __bf16 hh = (__bf16)gf[e + 8];
            lo[e] = __builtin_bit_cast(short, hl);
            hi[e] = __builtin_bit_cast(short, hh);
        }
        const int i = tid >> 4, j = tid & 15;
        const int c = j & 7, jaw = j >> 3;
        unsigned short* d0 = ldsb + ((c * 64 + 32 * jaw) + i) * 8;
        *reinterpret_cast<short8*>(d0)       = lo;
        *reinterpret_cast<short8*>(d0 + 128) = hi;
    }
    __syncthreads();

    short8 bfrag[8];
    #pragma unroll
    for (int c = 0; c < 8; ++c)
        bfrag[c] = *reinterpret_cast<const short8*>(ldsb + (c * 64 + lane) * 8);

    #pragma unroll
    for (int t = 0; t < TPW; ++t) {
        if (tile0 + t >= ntiles) continue;

        float xs[8] = {xa[t][0].x, xa[t][0].y, xa[t][0].z, xa[t][0].w,
                       xa[t][1].x, xa[t][1].y, xa[t][1].z, xa[t][1].w};
        float ys[8] = {ya[t][0].x, ya[t][0].y, ya[t][0].z, ya[t][0].w,
                       ya[t][1].x, ya[t][1].y, ya[t][1].z, ya[t][1].w};

        f32x4 acc = {0.f, 0.f, 0.f, 0.f};
        #pragma unroll
        for (int c = 0; c < 8; ++c) {
            float xj = xs[c];
            short8 a;
            #pragma unroll
            for (int e = 0; e < 8; ++e) {
                __bf16 h = (__bf16)(xj * ys[e]);
                a[e] = __builtin_bit_cast(short, h);
            }
            acc = __builtin_amdgcn_mfma_f32_16x16x32_bf16(a, bfrag[c], acc, 0, 0, 0);
        }

        float* op = out + ((size_t)(tile0 + t) * 16 + 4 * g) * MV + p;
        op[0 * MV] = acc[0];
        op[1 * MV] = acc[1];
        op[2 * MV] = acc[2];
        op[3 * MV] = acc[3];
    }
}

// ---------------------------------------------------------------------------
// fp32 fallback for shapes the MFMA path doesn't cover
// ---------------------------------------------------------------------------
__global__ __launch_bounds__(256) void gp_fp32_kernel(
    const float* __restrict__ g,
    const float* __restrict__ x,
    const float* __restrict__ y,
    float* __restrict__ out,
    int npix)
{
    int idx = blockIdx.x * blockDim.x + threadIdx.x;
    if (idx >= npix) return;

    const float4* xv = reinterpret_cast<const float4*>(x) + (size_t)idx * 4;
    const float4* yv = reinterpret_cast<const float4*>(y) + (size_t)idx * 4;

    float xr[MV], yr[MV], acc[MV];
    #pragma unroll
    for (int q = 0; q < 4; ++q) {
        float4 t = xv[q];
        xr[4*q+0] = t.x; xr[4*q+1] = t.y; xr[4*q+2] = t.z; xr[4*q+3] = t.w;
        float4 u = yv[q];
        yr[4*q+0] = u.x; yr[4*q+1] = u.y; yr[4*q+2] = u.z; yr[4*q+3] = u.w;
    }
    #pragma unroll
    for (int i = 0; i < MV; ++i) acc[i] = 0.0f;

    #pragma unroll
    for (int j = 0; j < MV; ++j) {
        #pragma unroll
        for (int k = 0; k < MV; ++k) {
            float pr = xr[j] * yr[k];
            #pragma unroll
            for (int i = 0; i < MV; ++i)
                acc[i] = fmaf(g[(i * MV + j) * MV + k], pr, acc[i]);
        }
    }

    float4* ov = reinterpret_cast<float4*>(out) + (size_t)idx * 4;
    #pragma unroll
    for (int q = 0; q < 4; ++q)
        ov[q] = make_float4(acc[4*q+0], acc[4*q+1], acc[4*q+2], acc[4*q+3]);
}

extern "C" void kernel_launch(void* const* d_in, const int* in_sizes, int n_in,
                              void* d_out, int out_size, void* d_ws, size_t ws_size,
                              hipStream_t stream) {
    const float* gp = (const float*)d_in[0];   // [16,16,16]
    const float* x  = (const float*)d_in[1];   // [npix,16]
    const float* y  = (const float*)d_in[2];   // [npix,16]
    float* out      = (float*)d_out;           // [npix,16]

    int npix = in_sizes[1] / MV;
    constexpr int TPWAVE = 8;   // tiles per wave, pipelined in pairs

    if ((npix % 16) == 0) {
        int ntiles = npix / 16;
        if (ntiles % (4 * TPWAVE) == 0) {
            int blocks = ntiles / (4 * TPWAVE);   // 1024 for npix=524288
            gp_pipe_kernel<TPWAVE><<<blocks, 256, 0, stream>>>(gp, x, y, out);
        } else {
            constexpr int TPW = 4;
            int blocks = (ntiles + 4 * TPW - 1) / (4 * TPW);
            gp_fused_kernel<TPW><<<blocks, 256, 0, stream>>>(gp, x, y, out, ntiles);
        }
    } else {
        int blocks = (npix + 255) / 256;
        gp_fp32_kernel<<<blocks, 256, 0, stream>>>(gp, x, y, out, npix);
    }
}